// Round 6
// baseline (10203.912 us; speedup 1.0000x reference)
//
#include <hip/hip_runtime.h>
#include <cstdint>

#define B_  64
#define T_  1024
#define I_  256
#define H_  512

typedef _Float16 h2_t __attribute__((ext_vector_type(2)));
typedef int sv16 __attribute__((ext_vector_type(16)));

__device__ __forceinline__ uint16_t f2h(float f) {
  _Float16 h = (_Float16)f;                        // v_cvt_f16_f32, RNE
  return __builtin_bit_cast(uint16_t, h);
}
__device__ __forceinline__ float dot2(uint32_t a, uint32_t b, float c) {
  return __builtin_amdgcn_fdot2(__builtin_bit_cast(h2_t, a),
                                __builtin_bit_cast(h2_t, b), c, false);
}
__device__ __forceinline__ float fast_tanh(float s) {
  float e = __expf(2.0f * s);
  return fmaf(-2.0f, __builtin_amdgcn_rcpf(e + 1.0f), 1.0f);
}

// select h pair P (0..63 within one h-quarter) from 4x16 SGPR vectors
template<int P>
__device__ __forceinline__ uint32_t hsel(sv16 h0, sv16 h1, sv16 h2, sv16 h3) {
  if constexpr (P < 16)      return (uint32_t)h0[P];
  else if constexpr (P < 32) return (uint32_t)h1[P - 16];
  else if constexpr (P < 48) return (uint32_t)h2[P - 32];
  else                       return (uint32_t)h3[P - 48];
}

// Pack ONE W_hh into f16-pair stream at ws[0:512KB).
// Layout: [k8 (64)][j (512)][m (4)] u32; u32 m at (k8,j) = (W[k][j],W[k+1][j]), k=8*k8+2m.
__global__ void pack_whh(const float* __restrict__ W, uint32_t* __restrict__ out) {
  int idx = blockIdx.x * 256 + threadIdx.x;        // [0, 131072)
  int k8 = idx >> 11;
  int j  = (idx >> 2) & 511;
  int m  = idx & 3;
  int k  = k8 * 8 + m * 2;
  uint32_t lo = f2h(W[k * H_ + j]);
  uint32_t hi = f2h(W[(k + 1) * H_ + j]);
  out[idx] = lo | (hi << 16);
}

// Y[tile rows] = A[tile rows] @ W + bias.  Tile = 64 rows x 512 cols, block 256.
// Rows staged fully into LDS before any write -> safe for in-place (A == Y).
template<int K>
__global__ __launch_bounds__(256) void gemm_rows(const float* A,
    const float* __restrict__ W, const float* __restrict__ bias,
    float* Y) {
  __shared__ float As[64 * (K + 1)];
  const int tid = threadIdx.x;
  const size_t row0 = (size_t)blockIdx.x * 64;
  const float* Ab = A + row0 * K;
  for (int idx = tid * 4; idx < 64 * K; idx += 1024) {
    float4 v = *(const float4*)(Ab + idx);
    int rr = idx / K;
    int cc = idx - rr * K;
    float* dst = &As[rr * (K + 1) + cc];
    dst[0] = v.x; dst[1] = v.y; dst[2] = v.z; dst[3] = v.w;
  }
  __syncthreads();
  const int cg = tid & 15;
  const int rg = tid >> 4;
  float acc[4][32];
  #pragma unroll
  for (int i = 0; i < 32; ++i) {
    float bz = bias[cg + 16 * i];
    acc[0][i] = bz; acc[1][i] = bz; acc[2][i] = bz; acc[3][i] = bz;
  }
  const float* Wc = W + cg;
  for (int k = 0; k < K; ++k) {
    float a0 = As[(rg * 4 + 0) * (K + 1) + k];
    float a1 = As[(rg * 4 + 1) * (K + 1) + k];
    float a2 = As[(rg * 4 + 2) * (K + 1) + k];
    float a3 = As[(rg * 4 + 3) * (K + 1) + k];
    const float* Wk = Wc + (size_t)k * H_;
    #pragma unroll
    for (int i = 0; i < 32; ++i) {
      float w = Wk[16 * i];
      acc[0][i] = fmaf(a0, w, acc[0][i]);
      acc[1][i] = fmaf(a1, w, acc[1][i]);
      acc[2][i] = fmaf(a2, w, acc[2][i]);
      acc[3][i] = fmaf(a3, w, acc[3][i]);
    }
  }
  float* Yb = Y + row0 * H_;
  #pragma unroll
  for (int jj = 0; jj < 4; ++jj) {
    float* Yr = Yb + (size_t)(rg * 4 + jj) * H_ + cg;
    #pragma unroll
    for (int i = 0; i < 32; ++i) Yr[16 * i] = acc[jj][i];
  }
}

// ROW: one uint4 of W (8 k = 4 pairs) against h pairs 4m..4m+3, 4 acc chains.
#define ROW(m, WEXPR) { uint4 w_ = (WEXPR); \
  a0 = dot2(w_.x, hsel<4*(m)+0>(h0,h1,h2,h3), a0); \
  a1 = dot2(w_.y, hsel<4*(m)+1>(h0,h1,h2,h3), a1); \
  a2 = dot2(w_.z, hsel<4*(m)+2>(h0,h1,h2,h3), a2); \
  a3 = dot2(w_.w, hsel<4*(m)+3>(h0,h1,h2,h3), a3); }

// Load one h-quarter (128 f16 = 4 x s_load_dwordx16) into SGPRs.
// SINGLE asm block with the lgkmcnt(0) wait INSIDE and =&s early-clobber
// outputs: no compiler-inserted SGPR copy can observe an incomplete load,
// and no output range can alias the base-address input pair.
#define BATCH_LOAD(OFF0, OFF1, OFF2, OFF3) \
  asm volatile("s_load_dwordx16 %0, %4, " OFF0 "\n\t" \
               "s_load_dwordx16 %1, %4, " OFF1 "\n\t" \
               "s_load_dwordx16 %2, %4, " OFF2 "\n\t" \
               "s_load_dwordx16 %3, %4, " OFF3 "\n\t" \
               "s_waitcnt lgkmcnt(0)" \
               : "=&s"(h0), "=&s"(h1), "=&s"(h2), "=&s"(h3) : "s"(hbase)); \
  __builtin_amdgcn_sched_barrier(0);

// Quarter consume: 12 VGPR-resident slabs + 4 streamed slabs.
#define CONSQ(q, G) \
  ROW(0,  wrv[12*(q)+0])  ROW(1,  wrv[12*(q)+1])  ROW(2,  wrv[12*(q)+2]) \
  ROW(3,  wrv[12*(q)+3])  ROW(4,  wrv[12*(q)+4])  ROW(5,  wrv[12*(q)+5]) \
  ROW(6,  wrv[12*(q)+6])  ROW(7,  wrv[12*(q)+7])  ROW(8,  wrv[12*(q)+8]) \
  ROW(9,  wrv[12*(q)+9])  ROW(10, wrv[12*(q)+10]) ROW(11, wrv[12*(q)+11]) \
  ROW(12, G[0]) ROW(13, G[1]) ROW(14, G[2]) ROW(15, G[3])

// Persistent scan: one WG per batch, thread j owns hidden unit j.
// h broadcast via SGPRs (global round-trip + s_load_dwordx16 after s_dcache_inv).
// h is PING-PONG double-buffered (the R4 fix): h(t) stored to buf[t&1], read
// from buf[(t-1)&1] -- a fast wave's h(t) store can never overwrite addresses
// a slow wave is still s_load-ing for step t (the WAR race that poisoned R2-R4).
// W: 48 slabs pinned in 192 VGPRs, 16 slabs (4/quarter) streamed from L2,
// double-buffered (gA/gB), issued 1 quarter early.
// Slab map per quarter q: resident = k8 in [16q,16q+12), streamed = [16q+12,16q+16).
__global__ __launch_bounds__(512, 2) void rnn_scan(float* Y,
    const uint4* __restrict__ Wp, ushort* __restrict__ hb16,
    float* __restrict__ hn) {
  const int j = threadIdx.x;
  float* Yb = Y + (size_t)blockIdx.x * (T_ * H_);
  ushort* hp0 = hb16 + blockIdx.x * (2 * H_);      // ping
  ushort* hp1 = hp0 + H_;                          // pong

  // resident W: quarter q slabs 0..11  ->  wrv[12q .. 12q+11]
  uint4 wrv[48];
  #pragma unroll
  for (int q = 0; q < 4; ++q)
    #pragma unroll
    for (int r = 0; r < 12; ++r)
      wrv[12 * q + r] = Wp[(16 * q + r) * H_ + j];
  // pin: values become opaque asm results -> loads cannot sink/rematerialize
  #pragma unroll
  for (int m = 0; m < 48; ++m)
    asm volatile("" : "+v"(wrv[m].x), "+v"(wrv[m].y), "+v"(wrv[m].z), "+v"(wrv[m].w));

  // t = 0: h_prev = 0 -> h = tanh(xp); h(0) -> buf0
  float xp0 = Yb[j];
  float v = fast_tanh(xp0);
  hp0[j] = f2h(v);
  Yb[j] = v;
  const uint64_t hb0 = (uint64_t)(uintptr_t)hp0;
  const uint64_t hb1 = (uint64_t)(uintptr_t)hp1;
  asm volatile("s_waitcnt vmcnt(0) lgkmcnt(0)\n\ts_barrier\n\ts_dcache_inv" ::: "memory");

  const uint4* WpS = Wp + j;                       // + slab*H_ per access

  for (int t = 1; t < T_; ++t) {
    const uint64_t hbase = (t & 1) ? hb0 : hb1;    // read h(t-1) from buf[(t-1)&1]
    ushort* hst = (t & 1) ? hp1 : hp0;             // store h(t) to buf[t&1]
    float xpt = Yb[t * H_ + j];
    float a0 = 0.f, a1 = 0.f, a2 = 0.f, a3 = 0.f;
    sv16 h0, h1, h2, h3;
    uint4 gA[4], gB[4];
    #pragma unroll
    for (int s = 0; s < 4; ++s) gA[s] = WpS[(12 + s) * H_];   // q0 streamed

    BATCH_LOAD("0x0", "0x40", "0x80", "0xc0")      // h quarter 0
    #pragma unroll
    for (int s = 0; s < 4; ++s) gB[s] = WpS[(28 + s) * H_];   // q1 streamed
    CONSQ(0, gA)

    BATCH_LOAD("0x100", "0x140", "0x180", "0x1c0") // h quarter 1
    #pragma unroll
    for (int s = 0; s < 4; ++s) gA[s] = WpS[(44 + s) * H_];   // q2 streamed
    CONSQ(1, gB)

    BATCH_LOAD("0x200", "0x240", "0x280", "0x2c0") // h quarter 2
    #pragma unroll
    for (int s = 0; s < 4; ++s) gB[s] = WpS[(60 + s) * H_];   // q3 streamed
    CONSQ(2, gA)

    BATCH_LOAD("0x300", "0x340", "0x380", "0x3c0") // h quarter 3
    CONSQ(3, gB)

    float s = xpt + ((a0 + a1) + (a2 + a3));
    v = fast_tanh(s);
    hst[j] = f2h(v);
    // h store must be L2-visible before other waves' next-step s_loads
    asm volatile("s_waitcnt vmcnt(0)\n\ts_barrier\n\ts_dcache_inv" ::: "memory");
    Yb[t * H_ + j] = v;                            // drains under next step's compute
  }
  hn[blockIdx.x * H_ + j] = v;
}

extern "C" void kernel_launch(void* const* d_in, const int* in_sizes, int n_in,
                              void* d_out, int out_size, void* d_ws, size_t ws_size,
                              hipStream_t stream) {
  const float* x     = (const float*)d_in[0];
  const float* W_ih0 = (const float*)d_in[1];
  const float* W_hh0 = (const float*)d_in[2];
  const float* b0    = (const float*)d_in[3];
  const float* W_ih1 = (const float*)d_in[4];
  const float* W_hh1 = (const float*)d_in[5];
  const float* b1    = (const float*)d_in[6];

  float* Y  = (float*)d_out;                        // [64][1024][512]
  float* hn = Y + (size_t)B_ * T_ * H_;             // [2][64][512]
  uint32_t* Wp = (uint32_t*)d_ws;                   // [0,512KB): f16-packed W_hh (one layer at a time)
  ushort* hbuf = (ushort*)((char*)d_ws + 512 * 1024); // [512KB,640KB): per-block ping-pong h (f16)

  // layer 0
  pack_whh<<<512, 256, 0, stream>>>(W_hh0, Wp);
  gemm_rows<I_><<<1024, 256, 0, stream>>>(x, W_ih0, b0, Y);
  rnn_scan<<<B_, H_, 0, stream>>>(Y, (const uint4*)Wp, hbuf, hn);
  // layer 1 (re-pack Wp with W_hh1 after scan0 is done with it)
  pack_whh<<<512, 256, 0, stream>>>(W_hh1, Wp);
  gemm_rows<H_><<<1024, 256, 0, stream>>>(Y, W_ih1, b1, Y);
  rnn_scan<<<B_, H_, 0, stream>>>(Y, (const uint4*)Wp, hbuf, hn + B_ * H_);
}

// Round 7
// 7013.834 us; speedup vs baseline: 1.4548x; 1.4548x over previous
//
#include <hip/hip_runtime.h>
#include <cstdint>

#define B_  64
#define T_  1024
#define I_  256
#define H_  512

typedef _Float16 h2_t __attribute__((ext_vector_type(2)));
typedef int sv16 __attribute__((ext_vector_type(16)));

__device__ __forceinline__ uint16_t f2h(float f) {
  _Float16 h = (_Float16)f;                        // v_cvt_f16_f32, RNE
  return __builtin_bit_cast(uint16_t, h);
}
__device__ __forceinline__ float dot2(uint32_t a, uint32_t b, float c) {
  return __builtin_amdgcn_fdot2(__builtin_bit_cast(h2_t, a),
                                __builtin_bit_cast(h2_t, b), c, false);
}
__device__ __forceinline__ float fast_tanh(float s) {
  float e = __expf(2.0f * s);
  return fmaf(-2.0f, __builtin_amdgcn_rcpf(e + 1.0f), 1.0f);
}

// select h pair P (0..63 within one h-quarter) from 4x16 SGPR vectors
template<int P>
__device__ __forceinline__ uint32_t hsel(sv16 h0, sv16 h1, sv16 h2, sv16 h3) {
  if constexpr (P < 16)      return (uint32_t)h0[P];
  else if constexpr (P < 32) return (uint32_t)h1[P - 16];
  else if constexpr (P < 48) return (uint32_t)h2[P - 32];
  else                       return (uint32_t)h3[P - 48];
}

// Pack ONE W_hh into f16-pair stream at ws[0:512KB).
// Layout: [k8 (64)][j (512)][m (4)] u32; u32 m at (k8,j) = (W[k][j],W[k+1][j]), k=8*k8+2m.
__global__ void pack_whh(const float* __restrict__ W, uint32_t* __restrict__ out) {
  int idx = blockIdx.x * 256 + threadIdx.x;        // [0, 131072)
  int k8 = idx >> 11;
  int j  = (idx >> 2) & 511;
  int m  = idx & 3;
  int k  = k8 * 8 + m * 2;
  uint32_t lo = f2h(W[k * H_ + j]);
  uint32_t hi = f2h(W[(k + 1) * H_ + j]);
  out[idx] = lo | (hi << 16);
}

// Y[tile rows] = A[tile rows] @ W + bias.  Tile = 64 rows x 512 cols, block 256.
// Rows staged fully into LDS before any write -> safe for in-place (A == Y).
template<int K>
__global__ __launch_bounds__(256) void gemm_rows(const float* A,
    const float* __restrict__ W, const float* __restrict__ bias,
    float* Y) {
  __shared__ float As[64 * (K + 1)];
  const int tid = threadIdx.x;
  const size_t row0 = (size_t)blockIdx.x * 64;
  const float* Ab = A + row0 * K;
  for (int idx = tid * 4; idx < 64 * K; idx += 1024) {
    float4 v = *(const float4*)(Ab + idx);
    int rr = idx / K;
    int cc = idx - rr * K;
    float* dst = &As[rr * (K + 1) + cc];
    dst[0] = v.x; dst[1] = v.y; dst[2] = v.z; dst[3] = v.w;
  }
  __syncthreads();
  const int cg = tid & 15;
  const int rg = tid >> 4;
  float acc[4][32];
  #pragma unroll
  for (int i = 0; i < 32; ++i) {
    float bz = bias[cg + 16 * i];
    acc[0][i] = bz; acc[1][i] = bz; acc[2][i] = bz; acc[3][i] = bz;
  }
  const float* Wc = W + cg;
  for (int k = 0; k < K; ++k) {
    float a0 = As[(rg * 4 + 0) * (K + 1) + k];
    float a1 = As[(rg * 4 + 1) * (K + 1) + k];
    float a2 = As[(rg * 4 + 2) * (K + 1) + k];
    float a3 = As[(rg * 4 + 3) * (K + 1) + k];
    const float* Wk = Wc + (size_t)k * H_;
    #pragma unroll
    for (int i = 0; i < 32; ++i) {
      float w = Wk[16 * i];
      acc[0][i] = fmaf(a0, w, acc[0][i]);
      acc[1][i] = fmaf(a1, w, acc[1][i]);
      acc[2][i] = fmaf(a2, w, acc[2][i]);
      acc[3][i] = fmaf(a3, w, acc[3][i]);
    }
  }
  float* Yb = Y + row0 * H_;
  #pragma unroll
  for (int jj = 0; jj < 4; ++jj) {
    float* Yr = Yb + (size_t)(rg * 4 + jj) * H_ + cg;
    #pragma unroll
    for (int i = 0; i < 32; ++i) Yr[16 * i] = acc[jj][i];
  }
}

// ROW: one uint4 of W (8 k = 4 pairs) against h pairs 4m..4m+3, 4 acc chains.
#define ROW(m, WEXPR) { uint4 w_ = (WEXPR); \
  a0 = dot2(w_.x, hsel<4*(m)+0>(h0,h1,h2,h3), a0); \
  a1 = dot2(w_.y, hsel<4*(m)+1>(h0,h1,h2,h3), a1); \
  a2 = dot2(w_.z, hsel<4*(m)+2>(h0,h1,h2,h3), a2); \
  a3 = dot2(w_.w, hsel<4*(m)+3>(h0,h1,h2,h3), a3); }

// Load one h-quarter (128 f16 = 4 x s_load_dwordx16) into SGPRs.
// SINGLE asm block with the lgkmcnt(0) wait INSIDE and =&s early-clobber
// outputs: no compiler-inserted SGPR copy can observe an incomplete load,
// and no output range can alias the base-address input pair.
#define BATCH_LOAD(OFF0, OFF1, OFF2, OFF3) \
  asm volatile("s_load_dwordx16 %0, %4, " OFF0 "\n\t" \
               "s_load_dwordx16 %1, %4, " OFF1 "\n\t" \
               "s_load_dwordx16 %2, %4, " OFF2 "\n\t" \
               "s_load_dwordx16 %3, %4, " OFF3 "\n\t" \
               "s_waitcnt lgkmcnt(0)" \
               : "=&s"(h0), "=&s"(h1), "=&s"(h2), "=&s"(h3) : "s"(hbase)); \
  __builtin_amdgcn_sched_barrier(0);

// Quarter consume: 8 VGPR slabs + 4 LDS slabs + 4 streamed slabs.
// ROW(m) must see slab k8 = 16q+m: reg m<8, LDS m=8..11, streamed m=12..15.
#define CONSQ(q, G) \
  ROW(0,  wrv[8*(q)+0])  ROW(1,  wrv[8*(q)+1])  ROW(2,  wrv[8*(q)+2]) \
  ROW(3,  wrv[8*(q)+3])  ROW(4,  wrv[8*(q)+4])  ROW(5,  wrv[8*(q)+5]) \
  ROW(6,  wrv[8*(q)+6])  ROW(7,  wrv[8*(q)+7]) \
  ROW(8,  WL[(4*(q)+0)*512 + j]) ROW(9,  WL[(4*(q)+1)*512 + j]) \
  ROW(10, WL[(4*(q)+2)*512 + j]) ROW(11, WL[(4*(q)+3)*512 + j]) \
  ROW(12, G[0]) ROW(13, G[1]) ROW(14, G[2]) ROW(15, G[3])

// Persistent scan: one WG per batch, thread j owns hidden unit j.
// h broadcast via SGPRs (global ping-pong round-trip + s_load_dwordx16 after
// s_dcache_inv; ping-pong kills the R4 WAR race).
// W split across all three on-chip pipes, each under its capacity limit
// (the R6 fix -- 48-slab VGPR pin demanded ~260 regs > 256 cap and spilled):
//   32 slabs in 128 VGPRs (asm-pinned), 16 slabs in 128KB LDS,
//   16 slabs streamed from L2 (double-buffered gA/gB, issued 1 quarter early).
// Slab map per quarter q: reg = [16q,16q+8), LDS = [16q+8,16q+12), stream = rest.
__global__ __launch_bounds__(512, 2) void rnn_scan(float* Y,
    const uint4* __restrict__ Wp, ushort* __restrict__ hb16,
    float* __restrict__ hn) {
  __shared__ uint4 WL[16 * 512];                   // 128 KB
  const int j = threadIdx.x;
  float* Yb = Y + (size_t)blockIdx.x * (T_ * H_);
  ushort* hp0 = hb16 + blockIdx.x * (2 * H_);      // ping
  ushort* hp1 = hp0 + H_;                          // pong

  // resident W: quarter q slabs 0..7 -> wrv[8q .. 8q+7]
  uint4 wrv[32];
  #pragma unroll
  for (int q = 0; q < 4; ++q)
    #pragma unroll
    for (int r = 0; r < 8; ++r)
      wrv[8 * q + r] = Wp[(16 * q + r) * H_ + j];
  // LDS W: quarter q slabs 8..11 -> WL[4q .. 4q+3]
  #pragma unroll
  for (int q = 0; q < 4; ++q)
    #pragma unroll
    for (int l = 0; l < 4; ++l)
      WL[(4 * q + l) * 512 + j] = Wp[(16 * q + 8 + l) * H_ + j];
  // pin: values become opaque asm results -> loads cannot sink/rematerialize
  #pragma unroll
  for (int m = 0; m < 32; ++m)
    asm volatile("" : "+v"(wrv[m].x), "+v"(wrv[m].y), "+v"(wrv[m].z), "+v"(wrv[m].w));

  // t = 0: h_prev = 0 -> h = tanh(xp); h(0) -> buf0
  float xp0 = Yb[j];
  float v = fast_tanh(xp0);
  hp0[j] = f2h(v);
  Yb[j] = v;
  const uint64_t hb0 = (uint64_t)(uintptr_t)hp0;
  const uint64_t hb1 = (uint64_t)(uintptr_t)hp1;
  // drain h store (vm) + WL ds_writes (lgkm), sync, invalidate K$
  asm volatile("s_waitcnt vmcnt(0) lgkmcnt(0)\n\ts_barrier\n\ts_dcache_inv" ::: "memory");

  const uint4* WpS = Wp + j;                       // + slab*H_ per access

  for (int t = 1; t < T_; ++t) {
    const uint64_t hbase = (t & 1) ? hb0 : hb1;    // read h(t-1) from buf[(t-1)&1]
    ushort* hst = (t & 1) ? hp1 : hp0;             // store h(t) to buf[t&1]
    float xpt = Yb[t * H_ + j];
    float a0 = 0.f, a1 = 0.f, a2 = 0.f, a3 = 0.f;
    sv16 h0, h1, h2, h3;
    uint4 gA[4], gB[4];
    #pragma unroll
    for (int s = 0; s < 4; ++s) gA[s] = WpS[(12 + s) * H_];   // q0 streamed

    BATCH_LOAD("0x0", "0x40", "0x80", "0xc0")      // h quarter 0
    #pragma unroll
    for (int s = 0; s < 4; ++s) gB[s] = WpS[(28 + s) * H_];   // q1 streamed
    CONSQ(0, gA)

    BATCH_LOAD("0x100", "0x140", "0x180", "0x1c0") // h quarter 1
    #pragma unroll
    for (int s = 0; s < 4; ++s) gA[s] = WpS[(44 + s) * H_];   // q2 streamed
    CONSQ(1, gB)

    BATCH_LOAD("0x200", "0x240", "0x280", "0x2c0") // h quarter 2
    #pragma unroll
    for (int s = 0; s < 4; ++s) gB[s] = WpS[(60 + s) * H_];   // q3 streamed
    CONSQ(2, gA)

    BATCH_LOAD("0x300", "0x340", "0x380", "0x3c0") // h quarter 3
    CONSQ(3, gB)

    float s = xpt + ((a0 + a1) + (a2 + a3));
    v = fast_tanh(s);
    hst[j] = f2h(v);
    // h store must be L2-visible before other waves' next-step s_loads
    asm volatile("s_waitcnt vmcnt(0)\n\ts_barrier\n\ts_dcache_inv" ::: "memory");
    Yb[t * H_ + j] = v;                            // drains under next step's compute
  }
  hn[blockIdx.x * H_ + j] = v;
}

extern "C" void kernel_launch(void* const* d_in, const int* in_sizes, int n_in,
                              void* d_out, int out_size, void* d_ws, size_t ws_size,
                              hipStream_t stream) {
  const float* x     = (const float*)d_in[0];
  const float* W_ih0 = (const float*)d_in[1];
  const float* W_hh0 = (const float*)d_in[2];
  const float* b0    = (const float*)d_in[3];
  const float* W_ih1 = (const float*)d_in[4];
  const float* W_hh1 = (const float*)d_in[5];
  const float* b1    = (const float*)d_in[6];

  float* Y  = (float*)d_out;                        // [64][1024][512]
  float* hn = Y + (size_t)B_ * T_ * H_;             // [2][64][512]
  uint32_t* Wp = (uint32_t*)d_ws;                   // [0,512KB): f16-packed W_hh (one layer at a time)
  ushort* hbuf = (ushort*)((char*)d_ws + 512 * 1024); // [512KB,640KB): per-block ping-pong h (f16)

  // layer 0
  pack_whh<<<512, 256, 0, stream>>>(W_hh0, Wp);
  gemm_rows<I_><<<1024, 256, 0, stream>>>(x, W_ih0, b0, Y);
  rnn_scan<<<B_, H_, 0, stream>>>(Y, (const uint4*)Wp, hbuf, hn);
  // layer 1 (re-pack Wp with W_hh1 after scan0 is done with it)
  pack_whh<<<512, 256, 0, stream>>>(W_hh1, Wp);
  gemm_rows<H_><<<1024, 256, 0, stream>>>(Y, W_ih1, b1, Y);
  rnn_scan<<<B_, H_, 0, stream>>>(Y, (const uint4*)Wp, hbuf, hn + B_ * H_);
}